// Round 1
// baseline (295.001 us; speedup 1.0000x reference)
//
#include <hip/hip_runtime.h>
#include <math.h>

#define HH 512
#define WW 512
#define PP (HH * WW)          // 262144 pixels
#define GG 64                 // gt points per batch
#define BB 4                  // batches
#define MAX_DIST 724.0773439350246f   // sqrt(512^2 + 512^2)
#define EPSV 1e-6f

// Workspace layout (floats):
//   ws[0..3]    t1_sum[b]
//   ws[4..7]    n_est[b]
//   ws[8..263]  gmin bits, uint, [b][g]  (non-negative floats -> uint order-preserving)

__global__ void ghd_init(float* __restrict__ ws) {
    int t = threadIdx.x;
    if (t < 8) ws[t] = 0.0f;
    unsigned* gm = reinterpret_cast<unsigned*>(ws) + 8;
    if (t < BB * GG) gm[t] = 0x7f7fffffu;  // FLT_MAX bits
}

__launch_bounds__(256, 4)
__global__ void ghd_main(const float* __restrict__ prob_map,
                         const float* __restrict__ prob_y,
                         const float* __restrict__ gt,
                         const int*   __restrict__ osz,
                         float*       __restrict__ ws) {
    const int b    = blockIdx.y;
    const int tid  = threadIdx.x;
    const int lane = tid & 63;
    const int wave = tid >> 6;

    __shared__ float4 gdat[GG];        // (ny0, ny1, py, py^2)
    __shared__ float  wmin[4][GG];     // per-wave per-g mins
    __shared__ float  s_t1[4], s_ne[4];

    const float nf0 = (float)osz[b * 2 + 0] * (1.0f / HH);
    const float nf1 = (float)osz[b * 2 + 1] * (1.0f / WW);

    if (tid < GG) {
        float g0 = gt[(b * GG + tid) * 2 + 0];
        float g1 = gt[(b * GG + tid) * 2 + 1];
        float py = prob_y[b * GG + tid];
        gdat[tid] = make_float4(nf0 * g0, nf1 * g1, py, py * py);
    }
    __syncthreads();

    float ming[GG];
#pragma unroll
    for (int g = 0; g < GG; ++g) ming[g] = 3.4e38f;

    float t1 = 0.0f, ne = 0.0f;

    const float* __restrict__ pm = prob_map + (size_t)b * PP;
    const int stride = gridDim.x * blockDim.x;
    for (int pid = blockIdx.x * blockDim.x + tid; pid < PP; pid += stride) {
        float p = pm[pid];
        int i = pid >> 9;          // pid / W
        int j = pid & (WW - 1);    // pid % W
        float nx0 = nf0 * (float)i;
        float nx1 = nf1 * (float)j;
        float base = (1.0f - p) * MAX_DIST;
        float m1q = 3.4e38f;
#pragma unroll
        for (int g = 0; g < GG; ++g) {
            float4 gd = gdat[g];
            float dx = nx0 - gd.x;
            float dy = nx1 - gd.y;
            float dist2 = fmaf(dx, dx, dy * dy);
            m1q = fminf(m1q, gd.w * dist2);          // tracks min_g (py^2 * d^2)
            float d = sqrtf(dist2);
            float dense = fmaf(p, gd.z * d, base);   // (1-p)*MAX + p*py*d
            ming[g] = fminf(ming[g], dense);
        }
        t1 = fmaf(p, sqrtf(m1q), t1);                // p * min_g(py*d)
        ne += p;
    }

    // ---- reductions ----
    // t1 / ne: wave sum
#pragma unroll
    for (int off = 1; off < 64; off <<= 1) {
        t1 += __shfl_xor(t1, off);
        ne += __shfl_xor(ne, off);
    }
    if (lane == 0) { s_t1[wave] = t1; s_ne[wave] = ne; }

    // ming[g]: wave min per g
#pragma unroll
    for (int g = 0; g < GG; ++g) {
        float v = ming[g];
        v = fminf(v, __shfl_xor(v, 1));
        v = fminf(v, __shfl_xor(v, 2));
        v = fminf(v, __shfl_xor(v, 4));
        v = fminf(v, __shfl_xor(v, 8));
        v = fminf(v, __shfl_xor(v, 16));
        v = fminf(v, __shfl_xor(v, 32));
        if (lane == 0) wmin[wave][g] = v;
    }
    __syncthreads();

    if (tid == 0) {
        atomicAdd(&ws[b],     s_t1[0] + s_t1[1] + s_t1[2] + s_t1[3]);
        atomicAdd(&ws[4 + b], s_ne[0] + s_ne[1] + s_ne[2] + s_ne[3]);
    }
    if (tid < GG) {
        float v = fminf(fminf(wmin[0][tid], wmin[1][tid]),
                        fminf(wmin[2][tid], wmin[3][tid]));
        unsigned* gm = reinterpret_cast<unsigned*>(ws) + 8;
        atomicMin(gm + b * GG + tid, __float_as_uint(v));
    }
}

__global__ void ghd_final(const float* __restrict__ prob_y,
                          const float* __restrict__ ws,
                          float*       __restrict__ out) {
    // 256 threads: wave b handles batch b (tid = b*64 + g)
    const int tid = threadIdx.x;
    const int b = tid >> 6;
    const int g = tid & 63;
    const unsigned* gm = reinterpret_cast<const unsigned*>(ws) + 8;

    float mv  = __uint_as_float(gm[b * GG + g]);
    float py  = prob_y[b * GG + g];
    float pyf = (py > 0.2f) ? py : 0.0f;
#pragma unroll
    for (int off = 1; off < 64; off <<= 1) {
        mv  += __shfl_xor(mv, off);
        pyf += __shfl_xor(pyf, off);
    }
    __shared__ float res[4];
    if (g == 0) {
        float term1 = ws[b]     / (ws[4 + b] + EPSV);
        float term2 = mv        / (pyf       + EPSV);
        res[b] = term1 + term2;
    }
    __syncthreads();
    if (tid == 0) out[0] = 0.25f * (res[0] + res[1] + res[2] + res[3]);
}

extern "C" void kernel_launch(void* const* d_in, const int* in_sizes, int n_in,
                              void* d_out, int out_size, void* d_ws, size_t ws_size,
                              hipStream_t stream) {
    const float* prob_map = (const float*)d_in[0];
    const float* prob_y   = (const float*)d_in[1];
    const float* gt       = (const float*)d_in[2];
    const int*   osz      = (const int*)d_in[3];
    float* out = (float*)d_out;
    float* ws  = (float*)d_ws;

    ghd_init<<<1, 256, 0, stream>>>(ws);
    dim3 grid(256, BB);
    ghd_main<<<grid, 256, 0, stream>>>(prob_map, prob_y, gt, osz, ws);
    ghd_final<<<1, 256, 0, stream>>>(prob_y, ws, out);
}